// Round 11
// baseline (463.667 us; speedup 1.0000x reference)
//
#include <hip/hip_runtime.h>
#include <hip/hip_bf16.h>
#include <math.h>

#define PDIM 10
#define HDIM 128
#define TDIM 138   // PDIM + HDIM
#define AROW 168   // A-tile LDS row stride in bf16
#define B_LEN (5 * 8 * 64 * 8)
#define TROW 136

// converted-weights layout (fp32, in ws)
#define CW_WQ 0
#define CW_WK 17664
#define CW_WV 35328
#define CW_WO 51712
#define CW_BQ 68096
#define CW_BK 68224
#define CW_BV 68352
#define CW_BO 68480
#define CW_GA 68608
#define CW_BE 68736
#define CW_TOTAL 68864

typedef short v8s __attribute__((ext_vector_type(8)));
typedef float v4f __attribute__((ext_vector_type(4)));
typedef float v2f __attribute__((ext_vector_type(2)));

#if defined(__has_builtin)
#if __has_builtin(__builtin_amdgcn_cvt_pk_f32_fp8) && __has_builtin(__builtin_amdgcn_cvt_pk_fp8_f32)
#define HAVE_FP8_CVT 1
#endif
#endif
#ifndef HAVE_FP8_CVT
#define HAVE_FP8_CVT 0
#endif

// ---------- bf16 helpers ----------
__device__ __forceinline__ float b2f_lo(unsigned u) { return __uint_as_float(u << 16); }
__device__ __forceinline__ float b2f_hi(unsigned u) { return __uint_as_float(u & 0xffff0000u); }
__device__ __forceinline__ unsigned short f2b(float f) {
    unsigned u = __float_as_uint(f);
    u += 0x7fffu + ((u >> 16) & 1u);
    return (unsigned short)(u >> 16);
}

// ---------- fp8 e4m3fn helpers (manual fallbacks are bit-faithful) ----------
__device__ __forceinline__ float f8_dec1(unsigned b) {
    unsigned e = (b >> 3) & 0xf, m = b & 7;
    float v = e ? __uint_as_float(((e + 120) << 23) | (m << 20))
                : (float)m * 0.001953125f;          // subnormal: m * 2^-9
    return (b & 0x80) ? -v : v;
}
__device__ __forceinline__ unsigned f8_enc1(float f) {
    unsigned u = __float_as_uint(f);
    unsigned s = (u >> 31) << 7;
    float a = fabsf(f);
    if (a < 0.0009765625f) return s;                // < 2^-10 -> 0
    if (a < 0.015625f) {                            // subnormal grid 2^-9
        int m = (int)(a * 512.f + 0.5f); if (m > 7) m = 7;
        return s | (unsigned)m;
    }
    if (a >= 448.f) return s | 0x7e;
    int ex = (int)((u >> 23) & 0xff);
    unsigned mant = u & 0x7fffff;
    unsigned r = mant >> 20, rem = mant & 0xfffff;
    if (rem > 0x80000u || (rem == 0x80000u && (r & 1))) r++;
    if (r == 8) { r = 0; ex++; }
    if (ex - 127 > 8) return s | 0x7e;
    return s | (unsigned)((ex - 120) << 3) | r;
}

// accumulate dot of 4 fp8 (one uint) against q[0..3]
__device__ __forceinline__ void dot4(unsigned w, const float* q, float& p) {
#if HAVE_FP8_CVT
    v2f lo = __builtin_amdgcn_cvt_pk_f32_fp8((int)w, false);
    v2f hi = __builtin_amdgcn_cvt_pk_f32_fp8((int)w, true);
    p = fmaf(q[0], lo[0], p); p = fmaf(q[1], lo[1], p);
    p = fmaf(q[2], hi[0], p); p = fmaf(q[3], hi[1], p);
#else
    p = fmaf(q[0], f8_dec1(w & 0xff), p);
    p = fmaf(q[1], f8_dec1((w >> 8) & 0xff), p);
    p = fmaf(q[2], f8_dec1((w >> 16) & 0xff), p);
    p = fmaf(q[3], f8_dec1(w >> 24), p);
#endif
}
// acc[0..3] += e * decode4(w)
__device__ __forceinline__ void acc4(unsigned w, float e, float* acc) {
#if HAVE_FP8_CVT
    v2f lo = __builtin_amdgcn_cvt_pk_f32_fp8((int)w, false);
    v2f hi = __builtin_amdgcn_cvt_pk_f32_fp8((int)w, true);
    acc[0] = fmaf(e, lo[0], acc[0]); acc[1] = fmaf(e, lo[1], acc[1]);
    acc[2] = fmaf(e, hi[0], acc[2]); acc[3] = fmaf(e, hi[1], acc[3]);
#else
    acc[0] = fmaf(e, f8_dec1(w & 0xff), acc[0]);
    acc[1] = fmaf(e, f8_dec1((w >> 8) & 0xff), acc[1]);
    acc[2] = fmaf(e, f8_dec1((w >> 16) & 0xff), acc[2]);
    acc[3] = fmaf(e, f8_dec1(w >> 24), acc[3]);
#endif
}
// pack 8 bf16 (uint4) -> 8 fp8 (uint2)
__device__ __forceinline__ uint2 pack8(uint4 t) {
#if HAVE_FP8_CVT
    int u0 = __builtin_amdgcn_cvt_pk_fp8_f32(b2f_lo(t.x), b2f_hi(t.x), 0, false);
    u0 = __builtin_amdgcn_cvt_pk_fp8_f32(b2f_lo(t.y), b2f_hi(t.y), u0, true);
    int u1 = __builtin_amdgcn_cvt_pk_fp8_f32(b2f_lo(t.z), b2f_hi(t.z), 0, false);
    u1 = __builtin_amdgcn_cvt_pk_fp8_f32(b2f_lo(t.w), b2f_hi(t.w), u1, true);
    return make_uint2((unsigned)u0, (unsigned)u1);
#else
    unsigned u0 = f8_enc1(b2f_lo(t.x)) | (f8_enc1(b2f_hi(t.x)) << 8)
                | (f8_enc1(b2f_lo(t.y)) << 16) | (f8_enc1(b2f_hi(t.y)) << 24);
    unsigned u1 = f8_enc1(b2f_lo(t.z)) | (f8_enc1(b2f_hi(t.z)) << 8)
                | (f8_enc1(b2f_lo(t.w)) << 16) | (f8_enc1(b2f_hi(t.w)) << 24);
    return make_uint2(u0, u1);
#endif
}

__global__ void ws_sentinel_kernel(float* out, int bucket)
{
    if (threadIdx.x == 0) out[0] = ldexpf(1.f + (float)bucket / 256.f, 100);
}

// =====================================================================
// K0: gather weights/biases into one contiguous fp32 block.
// =====================================================================
__global__ __launch_bounds__(256) void convert_weights(
    const float* Wq, const float* Wk, const float* Wv, const float* Wo,
    const float* bq, const float* bk, const float* bv, const float* bo,
    const float* ga, const float* be,
    float* __restrict__ dst)
{
    int idx = blockIdx.x * 256 + threadIdx.x;
    if (idx >= CW_TOTAL) return;
    const float* src; int loc;
    if      (idx < CW_WK) { src = Wq; loc = idx - CW_WQ; }
    else if (idx < CW_WV) { src = Wk; loc = idx - CW_WK; }
    else if (idx < CW_WO) { src = Wv; loc = idx - CW_WV; }
    else if (idx < CW_BQ) { src = Wo; loc = idx - CW_WO; }
    else if (idx < CW_BK) { src = bq; loc = idx - CW_BQ; }
    else if (idx < CW_BV) { src = bk; loc = idx - CW_BK; }
    else if (idx < CW_BO) { src = bv; loc = idx - CW_BV; }
    else if (idx < CW_GA) { src = bo; loc = idx - CW_BO; }
    else if (idx < CW_BE) { src = ga; loc = idx - CW_GA; }
    else                  { src = be; loc = idx - CW_BE; }
    dst[idx] = src[loc];
}

// =====================================================================
// K0c: pack Wq/Wk/Wv' into MFMA B-fragment-major bf16 (R8-verified).
// =====================================================================
__global__ __launch_bounds__(256) void pack_wfrag(
    const float* __restrict__ cw, unsigned short* __restrict__ wfrag)
{
    int g = blockIdx.x * 256 + threadIdx.x;
    if (g >= 3 * 5 * 8 * 64) return;
    int lane = g & 63;
    int nt   = (g >> 6) & 7;
    int mk   = g >> 9;
    int kc = mk % 5, mat = mk / 5;
    int quad = lane >> 4, l15 = lane & 15;
    int n = nt * 16 + l15;

    unsigned short* dst = wfrag + (size_t)g * 8;
    #pragma unroll
    for (int j = 0; j < 8; ++j) {
        int k = kc * 32 + quad * 8 + j;
        float v = 0.f;
        if (mat == 0)      { if (k < TDIM) v = cw[CW_WQ + k * HDIM + n]; }
        else if (mat == 1) { if (k < TDIM) v = cw[CW_WK + k * HDIM + n]; }
        else               { if (k >= PDIM && k < TDIM) v = cw[CW_WV + (k - PDIM) * HDIM + n]; }
        dst[j] = f2b(v);
    }
}

// =====================================================================
// K1-MFMA v2: fused Q,K,V GEMMs (R7-verified: 152 -> <85 us).
// =====================================================================
__global__ __launch_bounds__(256, 5) void qkv_mfma_kernel(
    const float* __restrict__ physics, const float* __restrict__ emb,
    const float* __restrict__ cw, const unsigned short* __restrict__ wfrag,
    unsigned short* __restrict__ Qb, unsigned char* __restrict__ K8,
    unsigned char* __restrict__ V8, int n_nodes)
{
    __shared__ __align__(16) unsigned short smem[64 * AROW];

    const int tid = threadIdx.x;
    const int nbase = blockIdx.x * 64;
    const int lane = tid & 63;
    const int w = tid >> 6;
    const int quad = lane >> 4;
    const int l15 = lane & 15;

    // ---- stage A-tile as bf16 pairs; row stride 84 dwords ----
    for (int idx = tid; idx < 64 * 5; idx += 256) {
        int r = idx / 5, p = idx - r * 5;
        int node = nbase + r;
        float v0 = 0.f, v1 = 0.f;
        if (node < n_nodes) {
            const float* ph = physics + (size_t)node * PDIM + 2 * p;
            v0 = ph[0]; v1 = ph[1];
        }
        ((unsigned*)smem)[r * 84 + p] = (unsigned)f2b(v0) | ((unsigned)f2b(v1) << 16);
    }
    for (int idx = tid; idx < 64 * 32; idx += 256) {
        int r = idx >> 5, c = idx & 31;
        int node = nbase + r;
        float4 e = make_float4(0.f, 0.f, 0.f, 0.f);
        if (node < n_nodes) e = *(const float4*)(emb + (size_t)node * HDIM + 4 * c);
        unsigned* dst = (unsigned*)smem + r * 84 + 5 + 2 * c;
        dst[0] = (unsigned)f2b(e.x) | ((unsigned)f2b(e.y) << 16);
        dst[1] = (unsigned)f2b(e.z) | ((unsigned)f2b(e.w) << 16);
    }
    for (int idx = tid; idx < 64 * 15; idx += 256) {
        int r = idx / 15, p = idx - r * 15;
        ((unsigned*)smem)[r * 84 + 69 + p] = 0;
    }
    __syncthreads();

    v8s a_frag[5];
    #pragma unroll
    for (int kc = 0; kc < 5; ++kc)
        a_frag[kc] = *(v8s*)(smem + (w * 16 + l15) * AROW + kc * 32 + quad * 8);
    __syncthreads();     // A-tile consumed; LDS now reused as T buffer

    const int r_out = tid >> 2;
    const int cseg = (tid & 3) * 32;
    const int node_out = nbase + r_out;

    for (int mat = 0; mat < 3; ++mat) {
        const v8s* bglob = (const v8s*)(wfrag + (size_t)mat * B_LEN) + lane;

        v4f acc[8];
        #pragma unroll
        for (int nt = 0; nt < 8; ++nt) acc[nt] = (v4f){0.f, 0.f, 0.f, 0.f};

        #pragma unroll
        for (int kc = 0; kc < 5; ++kc) {
            #pragma unroll
            for (int nt = 0; nt < 8; ++nt) {
                v8s b = bglob[(kc * 8 + nt) * 64];
                acc[nt] = __builtin_amdgcn_mfma_f32_16x16x32_bf16(
                    a_frag[kc], b, acc[nt], 0, 0, 0);
            }
        }

        #pragma unroll
        for (int nt = 0; nt < 8; ++nt) {
            float bias = cw[CW_BQ + mat * HDIM + nt * 16 + l15];
            #pragma unroll
            for (int reg = 0; reg < 4; ++reg) {
                int row = w * 16 + quad * 4 + reg;
                smem[row * TROW + nt * 16 + l15] = f2b(acc[nt][reg] + bias);
            }
        }
        __syncthreads();

        if (node_out < n_nodes) {
            const unsigned short* srcp = smem + r_out * TROW + cseg;
            if (mat == 0) {
                unsigned short* dst = Qb + (size_t)node_out * HDIM + cseg;
                #pragma unroll
                for (int j = 0; j < 4; ++j)
                    ((uint4*)dst)[j] = *(const uint4*)(srcp + 8 * j);
            } else {
                unsigned char* dst8 = (mat == 1 ? K8 : V8) + (size_t)node_out * HDIM + cseg;
                uint4 t0 = *(const uint4*)(srcp);
                uint4 t1 = *(const uint4*)(srcp + 8);
                uint4 t2 = *(const uint4*)(srcp + 16);
                uint4 t3 = *(const uint4*)(srcp + 24);
                uint2 p0 = pack8(t0), p1 = pack8(t1), p2 = pack8(t2), p3 = pack8(t3);
                ((uint4*)dst8)[0] = make_uint4(p0.x, p0.y, p1.x, p1.y);
                ((uint4*)dst8)[1] = make_uint4(p2.x, p2.y, p3.x, p3.y);
            }
        }
        if (mat < 2) __syncthreads();   // protect T before next overwrite
    }
}

// =====================================================================
// CSR build
// =====================================================================
__global__ __launch_bounds__(256) void degree_kernel(
    const int* __restrict__ ei, int* __restrict__ deg, int n_edges, int n_nodes)
{
    int e = blockIdx.x * 256 + threadIdx.x;
    if (e < n_edges) {
        int d = ei[n_edges + e];
        d = max(0, min(d, n_nodes - 1));
        atomicAdd(&deg[d], 1);
    }
}

__global__ __launch_bounds__(256) void scan_bsum(
    const int* __restrict__ deg, int* __restrict__ bsum, int n)
{
    __shared__ int s[256];
    int i = blockIdx.x * 256 + threadIdx.x;
    s[threadIdx.x] = (i < n) ? deg[i] : 0;
    __syncthreads();
    for (int off = 128; off > 0; off >>= 1) {
        if (threadIdx.x < off) s[threadIdx.x] += s[threadIdx.x + off];
        __syncthreads();
    }
    if (threadIdx.x == 0) bsum[blockIdx.x] = s[0];
}

__global__ __launch_bounds__(512) void scan_boff(
    const int* __restrict__ bsum, int* __restrict__ boff, int nb)
{
    __shared__ int s[512];
    int t = threadIdx.x;
    int v = (t < nb) ? bsum[t] : 0;
    s[t] = v;
    __syncthreads();
    for (int off = 1; off < 512; off <<= 1) {
        int u = (t >= off) ? s[t - off] : 0;
        __syncthreads();
        s[t] += u;
        __syncthreads();
    }
    if (t < nb) boff[t] = s[t] - v;
}

__global__ __launch_bounds__(256) void scan_final(
    const int* __restrict__ deg, const int* __restrict__ boff,
    int* __restrict__ row_off, int n)
{
    __shared__ int s[256];
    int t = threadIdx.x;
    int i = blockIdx.x * 256 + t;
    int v = (i < n) ? deg[i] : 0;
    s[t] = v;
    __syncthreads();
    for (int off = 1; off < 256; off <<= 1) {
        int u = (t >= off) ? s[t - off] : 0;
        __syncthreads();
        s[t] += u;
        __syncthreads();
    }
    int base = boff[blockIdx.x];
    if (i < n) row_off[i] = base + s[t] - v;
    if (i == n - 1) row_off[n] = base + s[t];
}

// =====================================================================
// fill v2: XCD-partitioned (R10: dropped out of top-5, exact gain TBD).
// =====================================================================
#define FILL_NPART 8
#define FILL_CHUNKS 512
__global__ __launch_bounds__(256) void fill_part_kernel(
    const int* __restrict__ ei, const int* __restrict__ row_off,
    int* __restrict__ cursor, int* __restrict__ csr_src, int n_edges, int n_nodes)
{
    const int part = blockIdx.x & (FILL_NPART - 1);
    const int chunk = blockIdx.x >> 3;
    const int W = (n_nodes + FILL_NPART - 1) / FILL_NPART;
    const int lo = part * W;
    const int hi = min(n_nodes, lo + W);
    const int epc = (n_edges + FILL_CHUNKS - 1) / FILL_CHUNKS;
    const int e0 = chunk * epc;
    const int e1 = min(n_edges, e0 + epc);

    for (int e = e0 + (int)threadIdx.x; e < e1; e += 256) {
        int d = ei[n_edges + e];
        d = max(0, min(d, n_nodes - 1));
        if (d >= lo && d < hi) {
            int pos = atomicAdd(&cursor[d], 1);
            csr_src[row_off[d] + pos] = ei[e];
        }
    }
}

// =====================================================================
// K5 v4: FUSED attention over FP8 K/V.  One wave per dst node.
// 16 edges in flight per iteration (2x8 batches, loads issued up front)
// -> doubles MLP, hides exp/load latency across batches.  deg~16 => 1 iter.
// =====================================================================
__global__ __launch_bounds__(256) void attn_fused_kernel(
    const unsigned short* __restrict__ Qb, const unsigned char* __restrict__ K8,
    const unsigned char* __restrict__ V8,
    const int* __restrict__ row_off, const int* __restrict__ csr_src,
    float* __restrict__ agg, int n_nodes, int n_edges)
{
    const int wid = (int)((blockIdx.x * 256 + threadIdx.x) >> 6);
    const int lane = threadIdx.x & 63;
    if (wid >= n_nodes) return;
    const int eg = lane >> 3;
    const int cg = lane & 7;

    const float scale = 0.088388347648318447f;   // 1/sqrt(128)
    const uint4* qp = (const uint4*)(Qb + (size_t)wid * HDIM + cg * 16);
    uint4 qa = qp[0], qb = qp[1];
    float q[16];
    q[0]  = b2f_lo(qa.x) * scale; q[1]  = b2f_hi(qa.x) * scale;
    q[2]  = b2f_lo(qa.y) * scale; q[3]  = b2f_hi(qa.y) * scale;
    q[4]  = b2f_lo(qa.z) * scale; q[5]  = b2f_hi(qa.z) * scale;
    q[6]  = b2f_lo(qa.w) * scale; q[7]  = b2f_hi(qa.w) * scale;
    q[8]  = b2f_lo(qb.x) * scale; q[9]  = b2f_hi(qb.x) * scale;
    q[10] = b2f_lo(qb.y) * scale; q[11] = b2f_hi(qb.y) * scale;
    q[12] = b2f_lo(qb.z) * scale; q[13] = b2f_hi(qb.z) * scale;
    q[14] = b2f_lo(qb.w) * scale; q[15] = b2f_hi(qb.w) * scale;

    int beg = row_off[wid], end = row_off[wid + 1];
    beg = max(0, min(beg, n_edges));
    end = max(beg, min(end, n_edges));

    float acc[16];
    #pragma unroll
    for (int j = 0; j < 16; ++j) acc[j] = 0.f;
    float den = 0.f;

    for (int i = beg; i < end; i += 16) {
        int idx0 = i + eg;
        int idx1 = i + 8 + eg;
        bool v0 = idx0 < end;
        bool v1 = idx1 < end;
        int s0 = csr_src[v0 ? idx0 : (end - 1)];
        int s1 = csr_src[v1 ? idx1 : (end - 1)];
        s0 = max(0, min(s0, n_nodes - 1));
        s1 = max(0, min(s1, n_nodes - 1));
        // issue all 4 gathers before any compute
        uint4 kr0 = *(const uint4*)(K8 + (size_t)s0 * HDIM + cg * 16);
        uint4 vr0 = *(const uint4*)(V8 + (size_t)s0 * HDIM + cg * 16);
        uint4 kr1 = *(const uint4*)(K8 + (size_t)s1 * HDIM + cg * 16);
        uint4 vr1 = *(const uint4*)(V8 + (size_t)s1 * HDIM + cg * 16);

        float p0 = 0.f, p1 = 0.f;
        dot4(kr0.x, q + 0, p0);
        dot4(kr0.y, q + 4, p0);
        dot4(kr0.z, q + 8, p0);
        dot4(kr0.w, q + 12, p0);
        dot4(kr1.x, q + 0, p1);
        dot4(kr1.y, q + 4, p1);
        dot4(kr1.z, q + 8, p1);
        dot4(kr1.w, q + 12, p1);
        p0 += __shfl_xor(p0, 1);
        p1 += __shfl_xor(p1, 1);
        p0 += __shfl_xor(p0, 2);
        p1 += __shfl_xor(p1, 2);
        p0 += __shfl_xor(p0, 4);
        p1 += __shfl_xor(p1, 4);

        float e0 = v0 ? __expf(fminf(p0, 60.f)) : 0.f;
        float e1 = v1 ? __expf(fminf(p1, 60.f)) : 0.f;
        den += e0 + e1;
        acc4(vr0.x, e0, acc + 0);
        acc4(vr0.y, e0, acc + 4);
        acc4(vr0.z, e0, acc + 8);
        acc4(vr0.w, e0, acc + 12);
        acc4(vr1.x, e1, acc + 0);
        acc4(vr1.y, e1, acc + 4);
        acc4(vr1.z, e1, acc + 8);
        acc4(vr1.w, e1, acc + 12);
    }

    #pragma unroll
    for (int j = 0; j < 16; ++j) {
        acc[j] += __shfl_xor(acc[j], 8);
        acc[j] += __shfl_xor(acc[j], 16);
        acc[j] += __shfl_xor(acc[j], 32);
    }
    den += __shfl_xor(den, 8);
    den += __shfl_xor(den, 16);
    den += __shfl_xor(den, 32);

    float inv = 1.f / (den + 1e-8f);
    if (eg == 0) {
        float* dst = agg + (size_t)wid * HDIM + cg * 16;
        #pragma unroll
        for (int j = 0; j < 4; ++j)
            *(float4*)(dst + 4 * j) = make_float4(acc[4*j] * inv, acc[4*j+1] * inv,
                                                 acc[4*j+2] * inv, acc[4*j+3] * inv);
    }
}

// =====================================================================
// K6 v2: out = agg@Wo + bo; x = emb + out; LayerNorm (in-place d_out).
// Node-major LDS (R10: dropped out of top-5, exact gain TBD).
// =====================================================================
#define LNROW 132
__global__ __launch_bounds__(256) void out_ln_kernel(
    const float* __restrict__ emb,
    const float* __restrict__ cw,
    float* __restrict__ out, int n_nodes)
{
    __shared__ float lds[32 * LNROW];
    const int tid = threadIdx.x;
    const int nbase = blockIdx.x * 32;

    // stage 32 node rows, node-major
    for (int idx = tid; idx < 32 * 32; idx += 256) {
        int m = idx >> 5;            // local node
        int cc = idx & 31;           // float4 column
        int node = nbase + m;
        float4 v = make_float4(0.f, 0.f, 0.f, 0.f);
        if (node < n_nodes) v = *(const float4*)(out + (size_t)node * HDIM + 4 * cc);
        *(float4*)(lds + m * LNROW + 4 * cc) = v;
    }
    __syncthreads();

    const int c = tid & 31;
    const int g = tid >> 5;
    const float* Wo = cw + CW_WO;

    float acc[4][4] = {{0.f}};
    for (int t = 0; t < HDIM; ++t) {
        float rr[4];
        #pragma unroll
        for (int m = 0; m < 4; ++m) rr[m] = lds[(4 * g + m) * LNROW + t];
        float4 w4 = *(const float4*)(Wo + t * HDIM + 4 * c);
        float wa[4] = { w4.x, w4.y, w4.z, w4.w };
        #pragma unroll
        for (int m = 0; m < 4; ++m)
            #pragma unroll
            for (int j = 0; j < 4; ++j)
                acc[m][j] = fmaf(rr[m], wa[j], acc[m][j]);
    }

    float4 bo4 = *(const float4*)(cw + CW_BO + 4 * c);
    float4 ga4 = *(const float4*)(cw + CW_GA + 4 * c);
    float4 be4 = *(const float4*)(cw + CW_BE + 4 * c);
    float boa[4] = { bo4.x, bo4.y, bo4.z, bo4.w };
    float ga[4]  = { ga4.x, ga4.y, ga4.z, ga4.w };
    float ba[4]  = { be4.x, be4.y, be4.z, be4.w };

    #pragma unroll
    for (int m = 0; m < 4; ++m) {
        int node = nbase + 4 * g + m;
        float ea[4] = { 0.f, 0.f, 0.f, 0.f };
        if (node < n_nodes) {
            float4 e4 = *(const float4*)(emb + (size_t)node * HDIM + 4 * c);
            ea[0] = e4.x; ea[1] = e4.y; ea[2] = e4.z; ea[3] = e4.w;
        }

        float x[4], s1 = 0.f, s2 = 0.f;
        #pragma unroll
        for (int j = 0; j < 4; ++j) {
            x[j] = ea[j] + acc[m][j] + boa[j];
            s1 += x[j];
            s2 = fmaf(x[j], x[j], s2);
        }
        #pragma unroll
        for (int mask = 1; mask <= 16; mask <<= 1) {
            s1 += __shfl_xor(s1, mask);
            s2 += __shfl_xor(s2, mask);
        }
        float mu = s1 * (1.f / 128.f);
        float var = fmaxf(s2 * (1.f / 128.f) - mu * mu, 0.f);
        float rs = rsqrtf(var + 1e-5f);
        if (node < n_nodes) {
            float4 o;
            o.x = ga[0] * (x[0] - mu) * rs + ba[0];
            o.y = ga[1] * (x[1] - mu) * rs + ba[1];
            o.z = ga[2] * (x[2] - mu) * rs + ba[2];
            o.w = ga[3] * (x[3] - mu) * rs + ba[3];
            *(float4*)(out + (size_t)node * HDIM + 4 * c) = o;
        }
    }
}

// =====================================================================
extern "C" void kernel_launch(void* const* d_in, const int* in_sizes, int n_in,
                              void* d_out, int out_size, void* d_ws, size_t ws_size,
                              hipStream_t stream)
{
    const float* physics = (const float*)d_in[0];
    const float* emb     = (const float*)d_in[1];
    const int*   ei      = (const int*)d_in[2];

    const int n_nodes = in_sizes[1] / HDIM;
    const int n_edges = in_sizes[2] / 2;
    const int NB = (n_nodes + 255) / 256;

    char* ws = (char*)d_ws;
    size_t off = 0;
    auto alloc = [&](size_t bytes) -> void* {
        void* p = ws + off;
        off = (off + bytes + 255) & ~(size_t)255;
        return p;
    };

    float* cw      = (float*)alloc((size_t)CW_TOTAL * 4);
    unsigned short* wfrag = (unsigned short*)alloc((size_t)3 * B_LEN * 2);
    int* deg       = (int*)alloc((size_t)2 * n_nodes * 4);
    int* cursor    = deg + n_nodes;
    int* row_off   = (int*)alloc((size_t)(n_nodes + 1) * 4);
    int* bsum      = (int*)alloc((size_t)NB * 4);
    int* boff      = (int*)alloc((size_t)NB * 4);
    int* csr_src   = (int*)alloc((size_t)n_edges * 4);
    unsigned short* Qb = (unsigned short*)alloc((size_t)n_nodes * HDIM * 2);
    unsigned char* K8  = (unsigned char*)alloc((size_t)n_nodes * HDIM);
    unsigned char* V8  = (unsigned char*)alloc((size_t)n_nodes * HDIM);

    if (ws_size < off) {
        int bucket = (int)min((size_t)255, ws_size >> 24);
        ws_sentinel_kernel<<<1, 64, 0, stream>>>((float*)d_out, bucket);
        return;
    }

    hipMemsetAsync(deg, 0, (size_t)2 * n_nodes * sizeof(int), stream);

    convert_weights<<<(CW_TOTAL + 255) / 256, 256, 0, stream>>>(
        (const float*)d_in[3], (const float*)d_in[5], (const float*)d_in[7],
        (const float*)d_in[9], (const float*)d_in[4], (const float*)d_in[6],
        (const float*)d_in[8], (const float*)d_in[10], (const float*)d_in[11],
        (const float*)d_in[12], cw);

    pack_wfrag<<<(3 * 5 * 8 * 64 + 255) / 256, 256, 0, stream>>>(cw, wfrag);
    qkv_mfma_kernel<<<(n_nodes + 63) / 64, 256, 0, stream>>>(
        physics, emb, cw, wfrag, Qb, K8, V8, n_nodes);

    degree_kernel<<<(n_edges + 255) / 256, 256, 0, stream>>>(ei, deg, n_edges, n_nodes);
    scan_bsum<<<NB, 256, 0, stream>>>(deg, bsum, n_nodes);
    scan_boff<<<1, 512, 0, stream>>>(bsum, boff, NB);
    scan_final<<<NB, 256, 0, stream>>>(deg, boff, row_off, n_nodes);
    fill_part_kernel<<<FILL_NPART * FILL_CHUNKS, 256, 0, stream>>>(
        ei, row_off, cursor, csr_src, n_edges, n_nodes);

    attn_fused_kernel<<<(n_nodes + 3) / 4, 256, 0, stream>>>(
        Qb, K8, V8, row_off, csr_src, (float*)d_out, n_nodes, n_edges);

    out_ln_kernel<<<(n_nodes + 31) / 32, 256, 0, stream>>>(
        emb, cw, (float*)d_out, n_nodes);
}

// Round 13
// 427.129 us; speedup vs baseline: 1.0855x; 1.0855x over previous
//
#include <hip/hip_runtime.h>
#include <hip/hip_bf16.h>
#include <math.h>

#define PDIM 10
#define HDIM 128
#define TDIM 138   // PDIM + HDIM
#define AROW 168   // A-tile LDS row stride in bf16 (qkv)
#define AROW2 136  // A-tile LDS row stride for out_ln (K=128 + 8 pad)
#define B_LEN (5 * 8 * 64 * 8)
#define TROW 136

// converted-weights layout (fp32, in ws)
#define CW_WQ 0
#define CW_WK 17664
#define CW_WV 35328
#define CW_WO 51712
#define CW_BQ 68096
#define CW_BK 68224
#define CW_BV 68352
#define CW_BO 68480
#define CW_GA 68608
#define CW_BE 68736
#define CW_TOTAL 68864

typedef short v8s __attribute__((ext_vector_type(8)));
typedef float v4f __attribute__((ext_vector_type(4)));
typedef float v2f __attribute__((ext_vector_type(2)));

#if defined(__has_builtin)
#if __has_builtin(__builtin_amdgcn_cvt_pk_f32_fp8) && __has_builtin(__builtin_amdgcn_cvt_pk_fp8_f32)
#define HAVE_FP8_CVT 1
#endif
#endif
#ifndef HAVE_FP8_CVT
#define HAVE_FP8_CVT 0
#endif

// ---------- bf16 helpers ----------
__device__ __forceinline__ float b2f_lo(unsigned u) { return __uint_as_float(u << 16); }
__device__ __forceinline__ float b2f_hi(unsigned u) { return __uint_as_float(u & 0xffff0000u); }
__device__ __forceinline__ unsigned short f2b(float f) {
    unsigned u = __float_as_uint(f);
    u += 0x7fffu + ((u >> 16) & 1u);
    return (unsigned short)(u >> 16);
}

// ---------- fp8 e4m3fn helpers ----------
__device__ __forceinline__ float f8_dec1(unsigned b) {
    unsigned e = (b >> 3) & 0xf, m = b & 7;
    float v = e ? __uint_as_float(((e + 120) << 23) | (m << 20))
                : (float)m * 0.001953125f;
    return (b & 0x80) ? -v : v;
}
__device__ __forceinline__ unsigned f8_enc1(float f) {
    unsigned u = __float_as_uint(f);
    unsigned s = (u >> 31) << 7;
    float a = fabsf(f);
    if (a < 0.0009765625f) return s;
    if (a < 0.015625f) {
        int m = (int)(a * 512.f + 0.5f); if (m > 7) m = 7;
        return s | (unsigned)m;
    }
    if (a >= 448.f) return s | 0x7e;
    int ex = (int)((u >> 23) & 0xff);
    unsigned mant = u & 0x7fffff;
    unsigned r = mant >> 20, rem = mant & 0xfffff;
    if (rem > 0x80000u || (rem == 0x80000u && (r & 1))) r++;
    if (r == 8) { r = 0; ex++; }
    if (ex - 127 > 8) return s | 0x7e;
    return s | (unsigned)((ex - 120) << 3) | r;
}

__device__ __forceinline__ void dot4(unsigned w, const float* q, float& p) {
#if HAVE_FP8_CVT
    v2f lo = __builtin_amdgcn_cvt_pk_f32_fp8((int)w, false);
    v2f hi = __builtin_amdgcn_cvt_pk_f32_fp8((int)w, true);
    p = fmaf(q[0], lo[0], p); p = fmaf(q[1], lo[1], p);
    p = fmaf(q[2], hi[0], p); p = fmaf(q[3], hi[1], p);
#else
    p = fmaf(q[0], f8_dec1(w & 0xff), p);
    p = fmaf(q[1], f8_dec1((w >> 8) & 0xff), p);
    p = fmaf(q[2], f8_dec1((w >> 16) & 0xff), p);
    p = fmaf(q[3], f8_dec1(w >> 24), p);
#endif
}
__device__ __forceinline__ void acc4(unsigned w, float e, float* acc) {
#if HAVE_FP8_CVT
    v2f lo = __builtin_amdgcn_cvt_pk_f32_fp8((int)w, false);
    v2f hi = __builtin_amdgcn_cvt_pk_f32_fp8((int)w, true);
    acc[0] = fmaf(e, lo[0], acc[0]); acc[1] = fmaf(e, lo[1], acc[1]);
    acc[2] = fmaf(e, hi[0], acc[2]); acc[3] = fmaf(e, hi[1], acc[3]);
#else
    acc[0] = fmaf(e, f8_dec1(w & 0xff), acc[0]);
    acc[1] = fmaf(e, f8_dec1((w >> 8) & 0xff), acc[1]);
    acc[2] = fmaf(e, f8_dec1((w >> 16) & 0xff), acc[2]);
    acc[3] = fmaf(e, f8_dec1(w >> 24), acc[3]);
#endif
}
__device__ __forceinline__ uint2 pack8(uint4 t) {
#if HAVE_FP8_CVT
    int u0 = __builtin_amdgcn_cvt_pk_fp8_f32(b2f_lo(t.x), b2f_hi(t.x), 0, false);
    u0 = __builtin_amdgcn_cvt_pk_fp8_f32(b2f_lo(t.y), b2f_hi(t.y), u0, true);
    int u1 = __builtin_amdgcn_cvt_pk_fp8_f32(b2f_lo(t.z), b2f_hi(t.z), 0, false);
    u1 = __builtin_amdgcn_cvt_pk_fp8_f32(b2f_lo(t.w), b2f_hi(t.w), u1, true);
    return make_uint2((unsigned)u0, (unsigned)u1);
#else
    unsigned u0 = f8_enc1(b2f_lo(t.x)) | (f8_enc1(b2f_hi(t.x)) << 8)
                | (f8_enc1(b2f_lo(t.y)) << 16) | (f8_enc1(b2f_hi(t.y)) << 24);
    unsigned u1 = f8_enc1(b2f_lo(t.z)) | (f8_enc1(b2f_hi(t.z)) << 8)
                | (f8_enc1(b2f_lo(t.w)) << 16) | (f8_enc1(b2f_hi(t.w)) << 24);
    return make_uint2(u0, u1);
#endif
}

__global__ void ws_sentinel_kernel(float* out, int bucket)
{
    if (threadIdx.x == 0) out[0] = ldexpf(1.f + (float)bucket / 256.f, 100);
}

// =====================================================================
// K0: gather weights/biases into one contiguous fp32 block.
// =====================================================================
__global__ __launch_bounds__(256) void convert_weights(
    const float* Wq, const float* Wk, const float* Wv, const float* Wo,
    const float* bq, const float* bk, const float* bv, const float* bo,
    const float* ga, const float* be,
    float* __restrict__ dst)
{
    int idx = blockIdx.x * 256 + threadIdx.x;
    if (idx >= CW_TOTAL) return;
    const float* src; int loc;
    if      (idx < CW_WK) { src = Wq; loc = idx - CW_WQ; }
    else if (idx < CW_WV) { src = Wk; loc = idx - CW_WK; }
    else if (idx < CW_WO) { src = Wv; loc = idx - CW_WV; }
    else if (idx < CW_BQ) { src = Wo; loc = idx - CW_WO; }
    else if (idx < CW_BK) { src = bq; loc = idx - CW_BQ; }
    else if (idx < CW_BV) { src = bk; loc = idx - CW_BK; }
    else if (idx < CW_BO) { src = bv; loc = idx - CW_BV; }
    else if (idx < CW_GA) { src = bo; loc = idx - CW_BO; }
    else if (idx < CW_BE) { src = ga; loc = idx - CW_GA; }
    else                  { src = be; loc = idx - CW_BE; }
    dst[idx] = src[loc];
}

// =====================================================================
// K0c: pack Wq/Wk/Wv'/Wo into MFMA B-fragment-major bf16.
// mat 0..2: R8-verified; mat 3 = Wo (K=128, kc chunk 4 zero-padded).
// =====================================================================
__global__ __launch_bounds__(256) void pack_wfrag(
    const float* __restrict__ cw, unsigned short* __restrict__ wfrag)
{
    int g = blockIdx.x * 256 + threadIdx.x;
    if (g >= 4 * 5 * 8 * 64) return;
    int lane = g & 63;
    int nt   = (g >> 6) & 7;
    int mk   = g >> 9;
    int kc = mk % 5, mat = mk / 5;
    int quad = lane >> 4, l15 = lane & 15;
    int n = nt * 16 + l15;

    unsigned short* dst = wfrag + (size_t)g * 8;
    #pragma unroll
    for (int j = 0; j < 8; ++j) {
        int k = kc * 32 + quad * 8 + j;
        float v = 0.f;
        if (mat == 0)      { if (k < TDIM) v = cw[CW_WQ + k * HDIM + n]; }
        else if (mat == 1) { if (k < TDIM) v = cw[CW_WK + k * HDIM + n]; }
        else if (mat == 2) { if (k >= PDIM && k < TDIM) v = cw[CW_WV + (k - PDIM) * HDIM + n]; }
        else               { if (k < HDIM) v = cw[CW_WO + k * HDIM + n]; }
        dst[j] = f2b(v);
    }
}

// =====================================================================
// K1-MFMA v2: fused Q,K,V GEMMs (R7-verified: 152 -> <85 us).
// =====================================================================
__global__ __launch_bounds__(256, 5) void qkv_mfma_kernel(
    const float* __restrict__ physics, const float* __restrict__ emb,
    const float* __restrict__ cw, const unsigned short* __restrict__ wfrag,
    unsigned short* __restrict__ Qb, unsigned char* __restrict__ K8,
    unsigned char* __restrict__ V8, int n_nodes)
{
    __shared__ __align__(16) unsigned short smem[64 * AROW];

    const int tid = threadIdx.x;
    const int nbase = blockIdx.x * 64;
    const int lane = tid & 63;
    const int w = tid >> 6;
    const int quad = lane >> 4;
    const int l15 = lane & 15;

    for (int idx = tid; idx < 64 * 5; idx += 256) {
        int r = idx / 5, p = idx - r * 5;
        int node = nbase + r;
        float v0 = 0.f, v1 = 0.f;
        if (node < n_nodes) {
            const float* ph = physics + (size_t)node * PDIM + 2 * p;
            v0 = ph[0]; v1 = ph[1];
        }
        ((unsigned*)smem)[r * 84 + p] = (unsigned)f2b(v0) | ((unsigned)f2b(v1) << 16);
    }
    for (int idx = tid; idx < 64 * 32; idx += 256) {
        int r = idx >> 5, c = idx & 31;
        int node = nbase + r;
        float4 e = make_float4(0.f, 0.f, 0.f, 0.f);
        if (node < n_nodes) e = *(const float4*)(emb + (size_t)node * HDIM + 4 * c);
        unsigned* dst = (unsigned*)smem + r * 84 + 5 + 2 * c;
        dst[0] = (unsigned)f2b(e.x) | ((unsigned)f2b(e.y) << 16);
        dst[1] = (unsigned)f2b(e.z) | ((unsigned)f2b(e.w) << 16);
    }
    for (int idx = tid; idx < 64 * 15; idx += 256) {
        int r = idx / 15, p = idx - r * 15;
        ((unsigned*)smem)[r * 84 + 69 + p] = 0;
    }
    __syncthreads();

    v8s a_frag[5];
    #pragma unroll
    for (int kc = 0; kc < 5; ++kc)
        a_frag[kc] = *(v8s*)(smem + (w * 16 + l15) * AROW + kc * 32 + quad * 8);
    __syncthreads();     // A-tile consumed; LDS now reused as T buffer

    const int r_out = tid >> 2;
    const int cseg = (tid & 3) * 32;
    const int node_out = nbase + r_out;

    for (int mat = 0; mat < 3; ++mat) {
        const v8s* bglob = (const v8s*)(wfrag + (size_t)mat * B_LEN) + lane;

        v4f acc[8];
        #pragma unroll
        for (int nt = 0; nt < 8; ++nt) acc[nt] = (v4f){0.f, 0.f, 0.f, 0.f};

        #pragma unroll
        for (int kc = 0; kc < 5; ++kc) {
            #pragma unroll
            for (int nt = 0; nt < 8; ++nt) {
                v8s b = bglob[(kc * 8 + nt) * 64];
                acc[nt] = __builtin_amdgcn_mfma_f32_16x16x32_bf16(
                    a_frag[kc], b, acc[nt], 0, 0, 0);
            }
        }

        #pragma unroll
        for (int nt = 0; nt < 8; ++nt) {
            float bias = cw[CW_BQ + mat * HDIM + nt * 16 + l15];
            #pragma unroll
            for (int reg = 0; reg < 4; ++reg) {
                int row = w * 16 + quad * 4 + reg;
                smem[row * TROW + nt * 16 + l15] = f2b(acc[nt][reg] + bias);
            }
        }
        __syncthreads();

        if (node_out < n_nodes) {
            const unsigned short* srcp = smem + r_out * TROW + cseg;
            if (mat == 0) {
                unsigned short* dst = Qb + (size_t)node_out * HDIM + cseg;
                #pragma unroll
                for (int j = 0; j < 4; ++j)
                    ((uint4*)dst)[j] = *(const uint4*)(srcp + 8 * j);
            } else {
                unsigned char* dst8 = (mat == 1 ? K8 : V8) + (size_t)node_out * HDIM + cseg;
                uint4 t0 = *(const uint4*)(srcp);
                uint4 t1 = *(const uint4*)(srcp + 8);
                uint4 t2 = *(const uint4*)(srcp + 16);
                uint4 t3 = *(const uint4*)(srcp + 24);
                uint2 p0 = pack8(t0), p1 = pack8(t1), p2 = pack8(t2), p3 = pack8(t3);
                ((uint4*)dst8)[0] = make_uint4(p0.x, p0.y, p1.x, p1.y);
                ((uint4*)dst8)[1] = make_uint4(p2.x, p2.y, p3.x, p3.y);
            }
        }
        if (mat < 2) __syncthreads();   // protect T before next overwrite
    }
}

// =====================================================================
// CSR build
// =====================================================================
__global__ __launch_bounds__(256) void degree_kernel(
    const int* __restrict__ ei, int* __restrict__ deg, int n_edges, int n_nodes)
{
    int e = blockIdx.x * 256 + threadIdx.x;
    if (e < n_edges) {
        int d = ei[n_edges + e];
        d = max(0, min(d, n_nodes - 1));
        atomicAdd(&deg[d], 1);
    }
}

__global__ __launch_bounds__(256) void scan_bsum(
    const int* __restrict__ deg, int* __restrict__ bsum, int n)
{
    __shared__ int s[256];
    int i = blockIdx.x * 256 + threadIdx.x;
    s[threadIdx.x] = (i < n) ? deg[i] : 0;
    __syncthreads();
    for (int off = 128; off > 0; off >>= 1) {
        if (threadIdx.x < off) s[threadIdx.x] += s[threadIdx.x + off];
        __syncthreads();
    }
    if (threadIdx.x == 0) bsum[blockIdx.x] = s[0];
}

__global__ __launch_bounds__(512) void scan_boff(
    const int* __restrict__ bsum, int* __restrict__ boff, int nb)
{
    __shared__ int s[512];
    int t = threadIdx.x;
    int v = (t < nb) ? bsum[t] : 0;
    s[t] = v;
    __syncthreads();
    for (int off = 1; off < 512; off <<= 1) {
        int u = (t >= off) ? s[t - off] : 0;
        __syncthreads();
        s[t] += u;
        __syncthreads();
    }
    if (t < nb) boff[t] = s[t] - v;
}

__global__ __launch_bounds__(256) void scan_final(
    const int* __restrict__ deg, const int* __restrict__ boff,
    int* __restrict__ row_off, int n)
{
    __shared__ int s[256];
    int t = threadIdx.x;
    int i = blockIdx.x * 256 + t;
    int v = (i < n) ? deg[i] : 0;
    s[t] = v;
    __syncthreads();
    for (int off = 1; off < 256; off <<= 1) {
        int u = (t >= off) ? s[t - off] : 0;
        __syncthreads();
        s[t] += u;
        __syncthreads();
    }
    int base = boff[blockIdx.x];
    if (i < n) row_off[i] = base + s[t] - v;
    if (i == n - 1) row_off[n] = base + s[t];
}

// =====================================================================
// fill v2: XCD-partitioned (R8; verified faster, below top-5 cutoff).
// =====================================================================
#define FILL_NPART 8
#define FILL_CHUNKS 512
__global__ __launch_bounds__(256) void fill_part_kernel(
    const int* __restrict__ ei, const int* __restrict__ row_off,
    int* __restrict__ cursor, int* __restrict__ csr_src, int n_edges, int n_nodes)
{
    const int part = blockIdx.x & (FILL_NPART - 1);
    const int chunk = blockIdx.x >> 3;
    const int W = (n_nodes + FILL_NPART - 1) / FILL_NPART;
    const int lo = part * W;
    const int hi = min(n_nodes, lo + W);
    const int epc = (n_edges + FILL_CHUNKS - 1) / FILL_CHUNKS;
    const int e0 = chunk * epc;
    const int e1 = min(n_edges, e0 + epc);

    for (int e = e0 + (int)threadIdx.x; e < e1; e += 256) {
        int d = ei[n_edges + e];
        d = max(0, min(d, n_nodes - 1));
        if (d >= lo && d < hi) {
            int pos = atomicAdd(&cursor[d], 1);
            csr_src[row_off[d] + pos] = ei[e];
        }
    }
}

// =====================================================================
// K5 v3 (R10-verified 84us): FUSED attention over FP8 K/V, 8 edges/iter.
// R12: output written as bf16 (feeds MFMA out_ln).
// =====================================================================
__global__ __launch_bounds__(256) void attn_fused_kernel(
    const unsigned short* __restrict__ Qb, const unsigned char* __restrict__ K8,
    const unsigned char* __restrict__ V8,
    const int* __restrict__ row_off, const int* __restrict__ csr_src,
    unsigned short* __restrict__ aggb, int n_nodes, int n_edges)
{
    const int wid = (int)((blockIdx.x * 256 + threadIdx.x) >> 6);
    const int lane = threadIdx.x & 63;
    if (wid >= n_nodes) return;
    const int eg = lane >> 3;
    const int cg = lane & 7;

    const float scale = 0.088388347648318447f;   // 1/sqrt(128)
    const uint4* qp = (const uint4*)(Qb + (size_t)wid * HDIM + cg * 16);
    uint4 qa = qp[0], qb = qp[1];
    float q[16];
    q[0]  = b2f_lo(qa.x) * scale; q[1]  = b2f_hi(qa.x) * scale;
    q[2]  = b2f_lo(qa.y) * scale; q[3]  = b2f_hi(qa.y) * scale;
    q[4]  = b2f_lo(qa.z) * scale; q[5]  = b2f_hi(qa.z) * scale;
    q[6]  = b2f_lo(qa.w) * scale; q[7]  = b2f_hi(qa.w) * scale;
    q[8]  = b2f_lo(qb.x) * scale; q[9]  = b2f_hi(qb.x) * scale;
    q[10] = b2f_lo(qb.y) * scale; q[11] = b2f_hi(qb.y) * scale;
    q[12] = b2f_lo(qb.z) * scale; q[13] = b2f_hi(qb.z) * scale;
    q[14] = b2f_lo(qb.w) * scale; q[15] = b2f_hi(qb.w) * scale;

    int beg = row_off[wid], end = row_off[wid + 1];
    beg = max(0, min(beg, n_edges));
    end = max(beg, min(end, n_edges));

    float acc[16];
    #pragma unroll
    for (int j = 0; j < 16; ++j) acc[j] = 0.f;
    float den = 0.f;

    for (int i = beg; i < end; i += 8) {
        int idx = i + eg;
        bool valid = idx < end;
        int s = csr_src[valid ? idx : (end - 1)];
        s = max(0, min(s, n_nodes - 1));
        uint4 kr = *(const uint4*)(K8 + (size_t)s * HDIM + cg * 16);
        uint4 vr = *(const uint4*)(V8 + (size_t)s * HDIM + cg * 16);

        float p = 0.f;
        dot4(kr.x, q + 0, p);
        dot4(kr.y, q + 4, p);
        dot4(kr.z, q + 8, p);
        dot4(kr.w, q + 12, p);
        p += __shfl_xor(p, 1);
        p += __shfl_xor(p, 2);
        p += __shfl_xor(p, 4);

        float e = valid ? __expf(fminf(p, 60.f)) : 0.f;
        den += e;
        acc4(vr.x, e, acc + 0);
        acc4(vr.y, e, acc + 4);
        acc4(vr.z, e, acc + 8);
        acc4(vr.w, e, acc + 12);
    }

    #pragma unroll
    for (int j = 0; j < 16; ++j) {
        acc[j] += __shfl_xor(acc[j], 8);
        acc[j] += __shfl_xor(acc[j], 16);
        acc[j] += __shfl_xor(acc[j], 32);
    }
    den += __shfl_xor(den, 8);
    den += __shfl_xor(den, 16);
    den += __shfl_xor(den, 32);

    float inv = 1.f / (den + 1e-8f);
    if (eg == 0) {
        unsigned* dst = (unsigned*)(aggb + (size_t)wid * HDIM + cg * 16);
        #pragma unroll
        for (int j = 0; j < 8; ++j)
            dst[j] = (unsigned)f2b(acc[2*j] * inv)
                   | ((unsigned)f2b(acc[2*j+1] * inv) << 16);
    }
}

// =====================================================================
// K6 v3 (MFMA): out = aggb@Wo + bo; x = emb + out; LayerNorm -> d_out.
// Structure cloned from verified qkv kernel: A = bf16 agg tile in LDS
// (stride 136 -> 2-way bank access, free), B = Wo fragments (mat=3),
// C-layout row = w*16+quad*4+reg, col = nt*16+l15 (R7/R8-verified).
// LN row-reduce: sum over nt in-register + shfl_xor 1,2,4,8 over l15.
// =====================================================================
__global__ __launch_bounds__(256) void out_ln_mfma_kernel(
    const unsigned short* __restrict__ aggb, const float* __restrict__ emb,
    const float* __restrict__ cw, const unsigned short* __restrict__ wfrag,
    float* __restrict__ out, int n_nodes)
{
    __shared__ __align__(16) unsigned short smem[64 * AROW2];
    const int tid = threadIdx.x;
    const int nbase = blockIdx.x * 64;
    const int lane = tid & 63;
    const int w = tid >> 6;
    const int quad = lane >> 4;
    const int l15 = lane & 15;

    // stage 64 node rows x 128 bf16 (16B chunks); rows 16B-aligned (272B stride)
    for (int idx = tid; idx < 64 * 16; idx += 256) {
        int r = idx >> 4, c = idx & 15;
        int node = nbase + r;
        uint4 v = make_uint4(0u, 0u, 0u, 0u);
        if (node < n_nodes) v = ((const uint4*)(aggb + (size_t)node * HDIM))[c];
        *(uint4*)((char*)smem + r * (AROW2 * 2) + c * 16) = v;
    }
    __syncthreads();

    v8s a_frag[4];
    #pragma unroll
    for (int kc = 0; kc < 4; ++kc)
        a_frag[kc] = *(v8s*)(smem + (w * 16 + l15) * AROW2 + kc * 32 + quad * 8);

    const v8s* bglob = (const v8s*)(wfrag + (size_t)3 * B_LEN) + lane;
    v4f acc[8];
    #pragma unroll
    for (int nt = 0; nt < 8; ++nt) acc[nt] = (v4f){0.f, 0.f, 0.f, 0.f};

    #pragma unroll
    for (int kc = 0; kc < 4; ++kc) {
        #pragma unroll
        for (int nt = 0; nt < 8; ++nt) {
            v8s b = bglob[(kc * 8 + nt) * 64];
            acc[nt] = __builtin_amdgcn_mfma_f32_16x16x32_bf16(
                a_frag[kc], b, acc[nt], 0, 0, 0);
        }
    }

    const int row = w * 16 + quad * 4;
    // x = gemm + bo + emb, stored in-place into acc
    #pragma unroll
    for (int nt = 0; nt < 8; ++nt) {
        int col = nt * 16 + l15;
        float bo_v = cw[CW_BO + col];
        #pragma unroll
        for (int reg = 0; reg < 4; ++reg) {
            int node = nbase + row + reg;
            float e = (node < n_nodes) ? emb[(size_t)node * HDIM + col] : 0.f;
            acc[nt][reg] += bo_v + e;
        }
    }

    float s1[4] = {0.f, 0.f, 0.f, 0.f};
    float s2[4] = {0.f, 0.f, 0.f, 0.f};
    #pragma unroll
    for (int nt = 0; nt < 8; ++nt)
        #pragma unroll
        for (int reg = 0; reg < 4; ++reg) {
            s1[reg] += acc[nt][reg];
            s2[reg] = fmaf(acc[nt][reg], acc[nt][reg], s2[reg]);
        }
    #pragma unroll
    for (int mask = 1; mask <= 8; mask <<= 1) {
        #pragma unroll
        for (int reg = 0; reg < 4; ++reg) {
            s1[reg] += __shfl_xor(s1[reg], mask);
            s2[reg] += __shfl_xor(s2[reg], mask);
        }
    }
    float mu[4], rs[4];
    #pragma unroll
    for (int reg = 0; reg < 4; ++reg) {
        mu[reg] = s1[reg] * (1.f / 128.f);
        float var = fmaxf(s2[reg] * (1.f / 128.f) - mu[reg] * mu[reg], 0.f);
        rs[reg] = rsqrtf(var + 1e-5f);
    }

    #pragma unroll
    for (int nt = 0; nt < 8; ++nt) {
        int col = nt * 16 + l15;
        float ga_v = cw[CW_GA + col];
        float be_v = cw[CW_BE + col];
        #pragma unroll
        for (int reg = 0; reg < 4; ++reg) {
            int node = nbase + row + reg;
            if (node < n_nodes)
                out[(size_t)node * HDIM + col] =
                    ga_v * (acc[nt][reg] - mu[reg]) * rs[reg] + be_v;
        }
    }
}

// =====================================================================
extern "C" void kernel_launch(void* const* d_in, const int* in_sizes, int n_in,
                              void* d_out, int out_size, void* d_ws, size_t ws_size,
                              hipStream_t stream)
{
    const float* physics = (const float*)d_in[0];
    const float* emb     = (const float*)d_in[1];
    const int*   ei      = (const int*)d_in[2];

    const int n_nodes = in_sizes[1] / HDIM;
    const int n_edges = in_sizes[2] / 2;
    const int NB = (n_nodes + 255) / 256;

    char* ws = (char*)d_ws;
    size_t off = 0;
    auto alloc = [&](size_t bytes) -> void* {
        void* p = ws + off;
        off = (off + bytes + 255) & ~(size_t)255;
        return p;
    };

    float* cw      = (float*)alloc((size_t)CW_TOTAL * 4);
    unsigned short* wfrag = (unsigned short*)alloc((size_t)4 * B_LEN * 2);
    int* deg       = (int*)alloc((size_t)2 * n_nodes * 4);
    int* cursor    = deg + n_nodes;
    int* row_off   = (int*)alloc((size_t)(n_nodes + 1) * 4);
    int* bsum      = (int*)alloc((size_t)NB * 4);
    int* boff      = (int*)alloc((size_t)NB * 4);
    int* csr_src   = (int*)alloc((size_t)n_edges * 4);
    unsigned short* Qb = (unsigned short*)alloc((size_t)n_nodes * HDIM * 2);
    unsigned char* K8  = (unsigned char*)alloc((size_t)n_nodes * HDIM);
    unsigned char* V8  = (unsigned char*)alloc((size_t)n_nodes * HDIM);
    unsigned short* aggb = (unsigned short*)alloc((size_t)n_nodes * HDIM * 2);

    if (ws_size < off) {
        int bucket = (int)min((size_t)255, ws_size >> 24);
        ws_sentinel_kernel<<<1, 64, 0, stream>>>((float*)d_out, bucket);
        return;
    }

    hipMemsetAsync(deg, 0, (size_t)2 * n_nodes * sizeof(int), stream);

    convert_weights<<<(CW_TOTAL + 255) / 256, 256, 0, stream>>>(
        (const float*)d_in[3], (const float*)d_in[5], (const float*)d_in[7],
        (const float*)d_in[9], (const float*)d_in[4], (const float*)d_in[6],
        (const float*)d_in[8], (const float*)d_in[10], (const float*)d_in[11],
        (const float*)d_in[12], cw);

    pack_wfrag<<<(4 * 5 * 8 * 64 + 255) / 256, 256, 0, stream>>>(cw, wfrag);
    qkv_mfma_kernel<<<(n_nodes + 63) / 64, 256, 0, stream>>>(
        physics, emb, cw, wfrag, Qb, K8, V8, n_nodes);

    degree_kernel<<<(n_edges + 255) / 256, 256, 0, stream>>>(ei, deg, n_edges, n_nodes);
    scan_bsum<<<NB, 256, 0, stream>>>(deg, bsum, n_nodes);
    scan_boff<<<1, 512, 0, stream>>>(bsum, boff, NB);
    scan_final<<<NB, 256, 0, stream>>>(deg, boff, row_off, n_nodes);
    fill_part_kernel<<<FILL_NPART * FILL_CHUNKS, 256, 0, stream>>>(
        ei, row_off, cursor, csr_src, n_edges, n_nodes);

    attn_fused_kernel<<<(n_nodes + 3) / 4, 256, 0, stream>>>(
        Qb, K8, V8, row_off, csr_src, aggb, n_nodes, n_edges);

    out_ln_mfma_kernel<<<(n_nodes + 63) / 64, 256, 0, stream>>>(
        aggb, emb, cw, wfrag, (float*)d_out, n_nodes);
}